// Round 1
// baseline (1291.499 us; speedup 1.0000x reference)
//
#include <hip/hip_runtime.h>
#include <cstdint>
#include <cstddef>

#define DIM    256
#define NE     2048
#define NROWS  65536
#define BM     64

// d_out flat fp32 layout: quantize_st | diff | embed_ind | perplexity
#define OFF_DIFF ((size_t)16777216)
#define OFF_IND  ((size_t)16777217)
#define OFF_PERP ((size_t)16842753)

// d_ws byte layout
#define WS_DIFF   0      // double
#define WS_CNT    64     // int[2048]
#define WS_EN     8256   // float[2048]
#define WS_ET     16448  // float[2048*256] (embed transposed), optional
#define WS_ET_NEED ((size_t)(16448 + (size_t)NE * DIM * 4))

// ||e_j||^2 for each code column j (double accumulate -> near-exact fp32)
__global__ __launch_bounds__(256) void k_prep(const float* __restrict__ embed,
                                              float* __restrict__ enorm) {
    int j = blockIdx.x * 256 + threadIdx.x;
    double s = 0.0;
    for (int d = 0; d < DIM; ++d) {
        float e = embed[(size_t)d * NE + j];
        s += (double)e * (double)e;
    }
    enorm[j] = (float)s;
}

// embed_T[j][d] = embed[d][j]  (coalesced writes, scattered L2 reads; 2MB)
__global__ __launch_bounds__(256) void k_transpose(const float* __restrict__ embed,
                                                   float* __restrict__ embedT) {
    int j0 = blockIdx.x * 8;
    for (int jj = 0; jj < 8; ++jj) {
        int j = j0 + jj;
        embedT[(size_t)j * DIM + threadIdx.x] = embed[(size_t)threadIdx.x * NE + j];
    }
}

// Main fused kernel: 64 rows/block. Score s_j = 2*x.e_j - ||e_j||^2, argmax over j,
// then gather + quantize write + diff partial + histogram.
__global__ __launch_bounds__(256) void k_main(const float* __restrict__ inp,
                                              const float* __restrict__ embed,
                                              const float* __restrict__ enorm,
                                              const float* __restrict__ embedT,
                                              int useT,
                                              float* __restrict__ out,
                                              int* __restrict__ counts,
                                              double* __restrict__ diffacc) {
    __shared__ float XsT[DIM][BM];   // exactly 64 KiB, [k][row]
    const int tid = threadIdx.x;
    const int m0  = blockIdx.x * BM;

    // ---- stage X transposed into LDS (once; staging bank conflicts amortized) ----
#pragma unroll
    for (int i = 0; i < 16; ++i) {
        int f   = tid + 256 * i;        // float4 index, 4096 total
        int row = f >> 6, c4 = f & 63;
        float4 v = *(const float4*)&inp[(size_t)(m0 + row) * DIM + c4 * 4];
        XsT[c4 * 4 + 0][row] = v.x;
        XsT[c4 * 4 + 1][row] = v.y;
        XsT[c4 * 4 + 2][row] = v.z;
        XsT[c4 * 4 + 3][row] = v.w;
    }
    __syncthreads();

    const int tx = tid & 15, ty = tid >> 4;   // 16x16 thread grid, 4x4 tile each
    float bv[4];
    int   bi[4];
#pragma unroll
    for (int mi = 0; mi < 4; ++mi) { bv[mi] = -1e30f; bi[mi] = 0x7fffffff; }

    for (int n0 = 0; n0 < NE; n0 += 64) {
        float acc[4][4] = {};
        const float* bp = embed + n0 + tx * 4;
        const float* ap = &XsT[0][ty * 4];
#pragma unroll 8
        for (int k = 0; k < DIM; ++k) {
            float4 b4 = *(const float4*)(bp + (size_t)k * NE);  // coalesced, L1/L2-hot
            float4 a4 = *(const float4*)(ap + k * BM);          // LDS broadcast
            acc[0][0] = fmaf(a4.x, b4.x, acc[0][0]);
            acc[0][1] = fmaf(a4.x, b4.y, acc[0][1]);
            acc[0][2] = fmaf(a4.x, b4.z, acc[0][2]);
            acc[0][3] = fmaf(a4.x, b4.w, acc[0][3]);
            acc[1][0] = fmaf(a4.y, b4.x, acc[1][0]);
            acc[1][1] = fmaf(a4.y, b4.y, acc[1][1]);
            acc[1][2] = fmaf(a4.y, b4.z, acc[1][2]);
            acc[1][3] = fmaf(a4.y, b4.w, acc[1][3]);
            acc[2][0] = fmaf(a4.z, b4.x, acc[2][0]);
            acc[2][1] = fmaf(a4.z, b4.y, acc[2][1]);
            acc[2][2] = fmaf(a4.z, b4.z, acc[2][2]);
            acc[2][3] = fmaf(a4.z, b4.w, acc[2][3]);
            acc[3][0] = fmaf(a4.w, b4.x, acc[3][0]);
            acc[3][1] = fmaf(a4.w, b4.y, acc[3][1]);
            acc[3][2] = fmaf(a4.w, b4.z, acc[3][2]);
            acc[3][3] = fmaf(a4.w, b4.w, acc[3][3]);
        }
        float4 en4 = *(const float4*)&enorm[n0 + tx * 4];
        int c0 = n0 + tx * 4;
#pragma unroll
        for (int mi = 0; mi < 4; ++mi) {
            float s0 = 2.f * acc[mi][0] - en4.x;
            float s1 = 2.f * acc[mi][1] - en4.y;
            float s2 = 2.f * acc[mi][2] - en4.z;
            float s3 = 2.f * acc[mi][3] - en4.w;
            float v = s0; int idx = c0;
            if (s1 > v) { v = s1; idx = c0 + 1; }
            if (s2 > v) { v = s2; idx = c0 + 2; }
            if (s3 > v) { v = s3; idx = c0 + 3; }
            // reduce across the 16 tx lanes (lane bits 0..3), first-index tie-break
#pragma unroll
            for (int o = 1; o < 16; o <<= 1) {
                float ov = __shfl_xor(v, o, 64);
                int   oi = __shfl_xor(idx, o, 64);
                if (ov > v || (ov == v && oi < idx)) { v = ov; idx = oi; }
            }
            if (v > bv[mi] || (v == bv[mi] && idx < bi[mi])) { bv[mi] = v; bi[mi] = idx; }
        }
    }

    __syncthreads();                       // everyone done reading XsT for GEMM
    int* sidx = (int*)&XsT[0][0];          // reuse LDS: 64 ints
    if (tx == 0) {
#pragma unroll
        for (int mi = 0; mi < 4; ++mi) {
            int rl = ty * 4 + mi;
            int idx = bi[mi];
            sidx[rl] = idx;
            out[OFF_IND + m0 + rl] = (float)idx;
            atomicAdd(&counts[idx], 1);
        }
    }
    __syncthreads();

    // gather codes + write quantize + commitment-loss partial
    float dsum = 0.f;
    for (int rl = 0; rl < BM; ++rl) {
        int idx = sidx[rl];
        float q = useT ? embedT[(size_t)idx * DIM + tid]
                       : embed[(size_t)tid * NE + idx];
        float x = inp[(size_t)(m0 + rl) * DIM + tid];
        out[(size_t)(m0 + rl) * DIM + tid] = q;
        float d = q - x;
        dsum = fmaf(d, d, dsum);
    }
    double ds = (double)dsum;
#pragma unroll
    for (int o = 32; o > 0; o >>= 1) ds += __shfl_down(ds, o, 64);
    double* red = (double*)&XsT[4][0];     // reuse LDS past sidx (offset 1 KiB)
    if ((tid & 63) == 0) red[tid >> 6] = ds;
    __syncthreads();
    if (tid == 0) atomicAdd(diffacc, red[0] + red[1] + red[2] + red[3]);
}

// perplexity + diff finalize
__global__ __launch_bounds__(256) void k_fin(const int* __restrict__ counts,
                                             const double* __restrict__ diffacc,
                                             float* __restrict__ out) {
    __shared__ double red[4];
    int tid = threadIdx.x;
    double s = 0.0;
    for (int i = tid; i < NE; i += 256) {
        int c = counts[i];
        if (c > 0) {
            float p = (float)c * (1.0f / 65536.0f);   // p >= 1/65536 > 1e-7, clip is no-op
            s += (double)(p * logf(p));
        }
    }
#pragma unroll
    for (int o = 32; o > 0; o >>= 1) s += __shfl_down(s, o, 64);
    if ((tid & 63) == 0) red[tid >> 6] = s;
    __syncthreads();
    if (tid == 0) {
        double t = red[0] + red[1] + red[2] + red[3];
        out[OFF_PERP] = expf((float)(-t));
        out[OFF_DIFF] = (float)(diffacc[0] * (1.0 / 16777216.0));
    }
}

extern "C" void kernel_launch(void* const* d_in, const int* in_sizes, int n_in,
                              void* d_out, int out_size, void* d_ws, size_t ws_size,
                              hipStream_t stream) {
    (void)in_sizes; (void)n_in; (void)out_size;
    const float* inp   = (const float*)d_in[0];
    const float* embed = (const float*)d_in[1];
    float* out = (float*)d_out;
    char*  ws  = (char*)d_ws;

    double* diffacc = (double*)(ws + WS_DIFF);
    int*    counts  = (int*)(ws + WS_CNT);
    float*  enorm   = (float*)(ws + WS_EN);
    float*  embedT  = (float*)(ws + WS_ET);
    int useT = (ws_size >= WS_ET_NEED) ? 1 : 0;

    hipMemsetAsync(d_ws, 0, 8256, stream);                 // diffacc + counts
    k_prep<<<NE / 256, 256, 0, stream>>>(embed, enorm);
    if (useT) k_transpose<<<DIM, 256, 0, stream>>>(embed, embedT);
    k_main<<<NROWS / BM, 256, 0, stream>>>(inp, embed, enorm,
                                           useT ? embedT : embed, useT,
                                           out, counts, diffacc);
    k_fin<<<1, 256, 0, stream>>>(counts, diffacc, out);
}

// Round 2
// 319.914 us; speedup vs baseline: 4.0370x; 4.0370x over previous
//
#include <hip/hip_runtime.h>
#include <cstdint>
#include <cstddef>

#define DIM    256
#define NE     2048
#define NROWS  65536

// d_out flat fp32 layout: quantize_st | diff | embed_ind | perplexity
#define OFF_DIFF ((size_t)16777216)
#define OFF_IND  ((size_t)16777217)
#define OFF_PERP ((size_t)16842753)

// d_ws byte layout
#define WS_DIFF   0                      // double
#define WS_CNT    64                     // int[2048]
#define WS_EN     8256                   // float[2048]
#define WS_ET     16448                  // float[2048*256] embedT
#define WS_BPH    2113600                // _Float16[2048*256] packed hi
#define WS_BPL    3162176                // _Float16[2048*256] packed lo
#define WS_NEED_V2 ((size_t)4210752)
#define WS_ET_NEED ((size_t)2113600)

typedef __attribute__((ext_vector_type(8))) _Float16 half8;
typedef __attribute__((ext_vector_type(4))) float    float4v;

__device__ __forceinline__ float4v mfma16(half8 a, half8 b, float4v c) {
    return __builtin_amdgcn_mfma_f32_16x16x32_f16(a, b, c, 0, 0, 0);
}

__device__ __forceinline__ void gld16(const void* g, void* l) {
    __builtin_amdgcn_global_load_lds((const __attribute__((address_space(1))) void*)g,
                                     (__attribute__((address_space(3))) void*)l,
                                     16, 0, 0);
}

// ---------------- small prep kernels ----------------

// ||e_j||^2 (double accumulate)
__global__ __launch_bounds__(256) void k_prep(const float* __restrict__ embed,
                                              float* __restrict__ enorm) {
    int j = blockIdx.x * 256 + threadIdx.x;
    double s = 0.0;
    for (int d = 0; d < DIM; ++d) {
        float e = embed[(size_t)d * NE + j];
        s += (double)e * (double)e;
    }
    enorm[j] = (float)s;
}

// embedT[j][d] = embed[d][j]
__global__ __launch_bounds__(256) void k_transpose(const float* __restrict__ embed,
                                                   float* __restrict__ embedT) {
    int j0 = blockIdx.x * 8;
    for (int jj = 0; jj < 8; ++jj) {
        int j = j0 + jj;
        embedT[(size_t)j * DIM + threadIdx.x] = embed[(size_t)threadIdx.x * NE + j];
    }
}

// pack embed into f16 hi/lo, MFMA-B-fragment order:
// elem16 idx = nc*1024 + kg*32 + n  holds k=kg*8..+7, col=nc*32+n
__global__ __launch_bounds__(256) void k_pack(const float* __restrict__ embed,
                                              _Float16* __restrict__ bph,
                                              _Float16* __restrict__ bpl) {
    int t   = blockIdx.x * 256 + threadIdx.x;   // 0..65535
    int col = t & (NE - 1);
    int kg  = t >> 11;                          // 0..31
    half8 h, l;
#pragma unroll
    for (int j = 0; j < 8; ++j) {
        float e = embed[(size_t)(kg * 8 + j) * NE + col];
        _Float16 eh = (_Float16)e;
        h[j] = eh;
        l[j] = (_Float16)(e - (float)eh);
    }
    size_t idx = (size_t)(col >> 5) * 1024 + (size_t)kg * 32 + (size_t)(col & 31);
    *(half8*)(bph + idx * 8) = h;
    *(half8*)(bpl + idx * 8) = l;
}

// ---------------- main fused MFMA kernel ----------------

__device__ __forceinline__ void stage_chunk(const char* srch, const char* srcl,
                                            char* dst, int w, int lane) {
#pragma unroll
    for (int s = 0; s < 4; ++s) {
        int seg = w * 4 + s;
        gld16(srch + seg * 1024 + lane * 16, dst + seg * 1024);
        gld16(srcl + seg * 1024 + lane * 16, dst + 16384 + seg * 1024);
    }
}

__global__ __launch_bounds__(256, 2) void k_gemm(
    const float* __restrict__ inp,
    const _Float16* __restrict__ bph,
    const _Float16* __restrict__ bpl,
    const float* __restrict__ enorm,
    const float* __restrict__ embedT,
    float* __restrict__ out,
    int* __restrict__ counts,
    double* __restrict__ diffacc)
{
    __shared__ __align__(16) char ldsB[2][32768];   // [buf]: hi 16KB | lo 16KB
    const int tid  = threadIdx.x;
    const int w    = tid >> 6;
    const int lane = tid & 63;
    const int q    = lane >> 4;
    const int nl   = lane & 15;
    const int m0   = blockIdx.x * 128;
    const int mw   = m0 + w * 32;

    // ---- A: 32 rows/wave stationary in registers, f16 hi+lo ----
    half8 ah[2][8], al[2][8];
#pragma unroll
    for (int mf = 0; mf < 2; ++mf) {
        const float* xr = inp + (size_t)(mw + mf * 16 + nl) * DIM + q * 8;
#pragma unroll
        for (int c = 0; c < 8; ++c) {
            float4 f0 = *(const float4*)(xr + c * 32);
            float4 f1 = *(const float4*)(xr + c * 32 + 4);
            float fs[8] = {f0.x, f0.y, f0.z, f0.w, f1.x, f1.y, f1.z, f1.w};
            half8 hh, ll;
#pragma unroll
            for (int j = 0; j < 8; ++j) {
                _Float16 xh = (_Float16)fs[j];
                hh[j] = xh;
                ll[j] = (_Float16)(fs[j] - (float)xh);
            }
            ah[mf][c] = hh;
            al[mf][c] = ll;
        }
    }

    // top-2 running state per (mfrag, reg)
    float sv1[2][4], sv2[2][4];
    int   si1[2][4], si2[2][4];
#pragma unroll
    for (int mf = 0; mf < 2; ++mf)
#pragma unroll
        for (int r = 0; r < 4; ++r) {
            sv1[mf][r] = -3.4e38f; sv2[mf][r] = -3.4e38f;
            si1[mf][r] = 0;        si2[mf][r] = 0;
        }

    stage_chunk((const char*)bph, (const char*)bpl, &ldsB[0][0], w, lane);
    __syncthreads();

    for (int nc = 0; nc < 64; ++nc) {
        int pn = nc & 1;
        if (nc < 63)
            stage_chunk((const char*)bph + (size_t)(nc + 1) * 16384,
                        (const char*)bpl + (size_t)(nc + 1) * 16384,
                        &ldsB[pn ^ 1][0], w, lane);

        const char* bb = &ldsB[pn][0] + q * 512 + nl * 16;
        float4v acc[2][2];
#pragma unroll
        for (int mf = 0; mf < 2; ++mf)
#pragma unroll
            for (int nf = 0; nf < 2; ++nf)
                acc[mf][nf] = (float4v){0.f, 0.f, 0.f, 0.f};

#pragma unroll
        for (int c = 0; c < 8; ++c) {
            half8 bh0 = *(const half8*)(bb + c * 2048);
            half8 bh1 = *(const half8*)(bb + c * 2048 + 256);
            half8 bl0 = *(const half8*)(bb + 16384 + c * 2048);
            half8 bl1 = *(const half8*)(bb + 16384 + c * 2048 + 256);
            acc[0][0] = mfma16(ah[0][c], bh0, acc[0][0]);
            acc[1][0] = mfma16(ah[1][c], bh0, acc[1][0]);
            acc[0][1] = mfma16(ah[0][c], bh1, acc[0][1]);
            acc[1][1] = mfma16(ah[1][c], bh1, acc[1][1]);
            acc[0][0] = mfma16(al[0][c], bh0, acc[0][0]);
            acc[1][0] = mfma16(al[1][c], bh0, acc[1][0]);
            acc[0][1] = mfma16(al[0][c], bh1, acc[0][1]);
            acc[1][1] = mfma16(al[1][c], bh1, acc[1][1]);
            acc[0][0] = mfma16(ah[0][c], bl0, acc[0][0]);
            acc[1][0] = mfma16(ah[1][c], bl0, acc[1][0]);
            acc[0][1] = mfma16(ah[0][c], bl1, acc[0][1]);
            acc[1][1] = mfma16(ah[1][c], bl1, acc[1][1]);
        }

        int colb = nc * 32;
#pragma unroll
        for (int nf = 0; nf < 2; ++nf) {
            int col = colb + nf * 16 + nl;
            float en05 = -0.5f * enorm[col];
#pragma unroll
            for (int mf = 0; mf < 2; ++mf) {
#pragma unroll
                for (int r = 0; r < 4; ++r) {
                    float s  = acc[mf][nf][r] + en05;
                    bool g1  = (s > sv1[mf][r]);
                    bool g2  = (s > sv2[mf][r]);
                    float nb2 = g1 ? sv1[mf][r] : (g2 ? s   : sv2[mf][r]);
                    int   ni2 = g1 ? si1[mf][r] : (g2 ? col : si2[mf][r]);
                    sv1[mf][r] = g1 ? s   : sv1[mf][r];
                    si1[mf][r] = g1 ? col : si1[mf][r];
                    sv2[mf][r] = nb2;
                    si2[mf][r] = ni2;
                }
            }
        }
        __syncthreads();
    }

    // ---- cross-lane top-2 merge over the 16 col-lanes ----
#pragma unroll
    for (int mf = 0; mf < 2; ++mf)
#pragma unroll
        for (int r = 0; r < 4; ++r) {
            float v1 = sv1[mf][r], v2 = sv2[mf][r];
            int   i1 = si1[mf][r], i2 = si2[mf][r];
#pragma unroll
            for (int msk = 1; msk < 16; msk <<= 1) {
                float ov1 = __shfl_xor(v1, msk); int oi1 = __shfl_xor(i1, msk);
                float ov2 = __shfl_xor(v2, msk); int oi2 = __shfl_xor(i2, msk);
                bool afirst = (v1 > ov1) || (v1 == ov1 && i1 < oi1);
                float cv = afirst ? ov1 : v1;  int ci = afirst ? oi1 : i1;
                float sv = afirst ? v2  : ov2; int si = afirst ? i2  : oi2;
                v1 = afirst ? v1 : ov1;        i1 = afirst ? i1 : oi1;
                bool sfirst = (sv > cv) || (sv == cv && si < ci);
                v2 = sfirst ? sv : cv;         i2 = sfirst ? si : ci;
            }
            si1[mf][r] = i1;
            si2[mf][r] = i2;
        }

    // ---- fused epilogue: exact fp32 rescore of top-2, gather, write, diff ----
    double dsum = 0.0;
#pragma unroll
    for (int mf = 0; mf < 2; ++mf)
#pragma unroll
        for (int qq = 0; qq < 4; ++qq)
#pragma unroll
            for (int r = 0; r < 4; ++r) {
                int i1 = __shfl(si1[mf][r], qq * 16);
                int i2 = __shfl(si2[mf][r], qq * 16);
                int row = mw + mf * 16 + qq * 4 + r;
                float4 xv = *(const float4*)(inp    + (size_t)row * DIM + lane * 4);
                float4 e1 = *(const float4*)(embedT + (size_t)i1  * DIM + lane * 4);
                float4 e2 = *(const float4*)(embedT + (size_t)i2  * DIM + lane * 4);
                float d1 = xv.x * e1.x + xv.y * e1.y + xv.z * e1.z + xv.w * e1.w;
                float d2 = xv.x * e2.x + xv.y * e2.y + xv.z * e2.z + xv.w * e2.w;
#pragma unroll
                for (int msk = 1; msk < 64; msk <<= 1) {
                    d1 += __shfl_xor(d1, msk);
                    d2 += __shfl_xor(d2, msk);
                }
                float s1 = 2.f * d1 - enorm[i1];
                float s2 = 2.f * d2 - enorm[i2];
                bool take2 = (s2 > s1) || (s2 == s1 && i2 < i1);
                int win = take2 ? i2 : i1;
                float4 qv = take2 ? e2 : e1;
                *(float4*)(out + (size_t)row * DIM + lane * 4) = qv;
                float dx = qv.x - xv.x, dy = qv.y - xv.y;
                float dz = qv.z - xv.z, dw = qv.w - xv.w;
                dsum += (double)(dx * dx + dy * dy + dz * dz + dw * dw);
                if (lane == 0) {
                    out[OFF_IND + row] = (float)win;
                    atomicAdd(&counts[win], 1);
                }
            }
#pragma unroll
    for (int msk = 1; msk < 64; msk <<= 1) dsum += __shfl_xor(dsum, msk);
    if (lane == 0) atomicAdd(diffacc, dsum);
}

// ---------------- round-1 fallback main kernel (small ws) ----------------
__global__ __launch_bounds__(256) void k_main(const float* __restrict__ inp,
                                              const float* __restrict__ embed,
                                              const float* __restrict__ enorm,
                                              const float* __restrict__ embedT,
                                              int useT,
                                              float* __restrict__ out,
                                              int* __restrict__ counts,
                                              double* __restrict__ diffacc) {
    __shared__ float XsT[DIM][64];
    const int tid = threadIdx.x;
    const int m0  = blockIdx.x * 64;
#pragma unroll
    for (int i = 0; i < 16; ++i) {
        int f = tid + 256 * i;
        int row = f >> 6, c4 = f & 63;
        float4 v = *(const float4*)&inp[(size_t)(m0 + row) * DIM + c4 * 4];
        XsT[c4 * 4 + 0][row] = v.x; XsT[c4 * 4 + 1][row] = v.y;
        XsT[c4 * 4 + 2][row] = v.z; XsT[c4 * 4 + 3][row] = v.w;
    }
    __syncthreads();
    const int tx = tid & 15, ty = tid >> 4;
    float bv[4]; int bi[4];
#pragma unroll
    for (int mi = 0; mi < 4; ++mi) { bv[mi] = -1e30f; bi[mi] = 0x7fffffff; }
    for (int n0 = 0; n0 < NE; n0 += 64) {
        float acc[4][4] = {};
        const float* bp = embed + n0 + tx * 4;
        const float* ap = &XsT[0][ty * 4];
#pragma unroll 8
        for (int k = 0; k < DIM; ++k) {
            float4 b4 = *(const float4*)(bp + (size_t)k * NE);
            float4 a4 = *(const float4*)(ap + k * 64);
            acc[0][0] = fmaf(a4.x, b4.x, acc[0][0]); acc[0][1] = fmaf(a4.x, b4.y, acc[0][1]);
            acc[0][2] = fmaf(a4.x, b4.z, acc[0][2]); acc[0][3] = fmaf(a4.x, b4.w, acc[0][3]);
            acc[1][0] = fmaf(a4.y, b4.x, acc[1][0]); acc[1][1] = fmaf(a4.y, b4.y, acc[1][1]);
            acc[1][2] = fmaf(a4.y, b4.z, acc[1][2]); acc[1][3] = fmaf(a4.y, b4.w, acc[1][3]);
            acc[2][0] = fmaf(a4.z, b4.x, acc[2][0]); acc[2][1] = fmaf(a4.z, b4.y, acc[2][1]);
            acc[2][2] = fmaf(a4.z, b4.z, acc[2][2]); acc[2][3] = fmaf(a4.z, b4.w, acc[2][3]);
            acc[3][0] = fmaf(a4.w, b4.x, acc[3][0]); acc[3][1] = fmaf(a4.w, b4.y, acc[3][1]);
            acc[3][2] = fmaf(a4.w, b4.z, acc[3][2]); acc[3][3] = fmaf(a4.w, b4.w, acc[3][3]);
        }
        float4 en4 = *(const float4*)&enorm[n0 + tx * 4];
        int c0 = n0 + tx * 4;
#pragma unroll
        for (int mi = 0; mi < 4; ++mi) {
            float s0 = 2.f * acc[mi][0] - en4.x, s1 = 2.f * acc[mi][1] - en4.y;
            float s2 = 2.f * acc[mi][2] - en4.z, s3 = 2.f * acc[mi][3] - en4.w;
            float v = s0; int idx = c0;
            if (s1 > v) { v = s1; idx = c0 + 1; }
            if (s2 > v) { v = s2; idx = c0 + 2; }
            if (s3 > v) { v = s3; idx = c0 + 3; }
#pragma unroll
            for (int o = 1; o < 16; o <<= 1) {
                float ov = __shfl_xor(v, o, 64); int oi = __shfl_xor(idx, o, 64);
                if (ov > v || (ov == v && oi < idx)) { v = ov; idx = oi; }
            }
            if (v > bv[mi] || (v == bv[mi] && idx < bi[mi])) { bv[mi] = v; bi[mi] = idx; }
        }
    }
    __syncthreads();
    int* sidx = (int*)&XsT[0][0];
    if (tx == 0) {
#pragma unroll
        for (int mi = 0; mi < 4; ++mi) {
            int rl = ty * 4 + mi; int idx = bi[mi];
            sidx[rl] = idx;
            out[OFF_IND + m0 + rl] = (float)idx;
            atomicAdd(&counts[idx], 1);
        }
    }
    __syncthreads();
    float dsum = 0.f;
    for (int rl = 0; rl < 64; ++rl) {
        int idx = sidx[rl];
        float qv = useT ? embedT[(size_t)idx * DIM + tid] : embed[(size_t)tid * NE + idx];
        float x = inp[(size_t)(m0 + rl) * DIM + tid];
        out[(size_t)(m0 + rl) * DIM + tid] = qv;
        float d = qv - x;
        dsum = fmaf(d, d, dsum);
    }
    double ds = (double)dsum;
#pragma unroll
    for (int o = 32; o > 0; o >>= 1) ds += __shfl_down(ds, o, 64);
    double* red = (double*)&XsT[4][0];
    if ((tid & 63) == 0) red[tid >> 6] = ds;
    __syncthreads();
    if (tid == 0) atomicAdd(diffacc, red[0] + red[1] + red[2] + red[3]);
}

// ---------------- finalize ----------------
__global__ __launch_bounds__(256) void k_fin(const int* __restrict__ counts,
                                             const double* __restrict__ diffacc,
                                             float* __restrict__ out) {
    __shared__ double red[4];
    int tid = threadIdx.x;
    double s = 0.0;
    for (int i = tid; i < NE; i += 256) {
        int c = counts[i];
        if (c > 0) {
            float p = (float)c * (1.0f / 65536.0f);
            s += (double)(p * logf(p));
        }
    }
#pragma unroll
    for (int o = 32; o > 0; o >>= 1) s += __shfl_down(s, o, 64);
    if ((tid & 63) == 0) red[tid >> 6] = s;
    __syncthreads();
    if (tid == 0) {
        double t = red[0] + red[1] + red[2] + red[3];
        out[OFF_PERP] = expf((float)(-t));
        out[OFF_DIFF] = (float)(diffacc[0] * (1.0 / 16777216.0));
    }
}

extern "C" void kernel_launch(void* const* d_in, const int* in_sizes, int n_in,
                              void* d_out, int out_size, void* d_ws, size_t ws_size,
                              hipStream_t stream) {
    (void)in_sizes; (void)n_in; (void)out_size;
    const float* inp   = (const float*)d_in[0];
    const float* embed = (const float*)d_in[1];
    float* out = (float*)d_out;
    char*  ws  = (char*)d_ws;

    double*   diffacc = (double*)(ws + WS_DIFF);
    int*      counts  = (int*)(ws + WS_CNT);
    float*    enorm   = (float*)(ws + WS_EN);
    float*    embedT  = (float*)(ws + WS_ET);
    _Float16* bph     = (_Float16*)(ws + WS_BPH);
    _Float16* bpl     = (_Float16*)(ws + WS_BPL);

    hipMemsetAsync(d_ws, 0, 8256, stream);   // diffacc + counts
    k_prep<<<NE / 256, 256, 0, stream>>>(embed, enorm);

    if (ws_size >= WS_NEED_V2) {
        k_transpose<<<DIM, 256, 0, stream>>>(embed, embedT);
        k_pack<<<NE * 32 / 256, 256, 0, stream>>>(embed, bph, bpl);
        k_gemm<<<NROWS / 128, 256, 0, stream>>>(inp, bph, bpl, enorm, embedT,
                                                out, counts, diffacc);
    } else {
        int useT = (ws_size >= WS_ET_NEED) ? 1 : 0;
        if (useT) k_transpose<<<DIM, 256, 0, stream>>>(embed, embedT);
        k_main<<<NROWS / 64, 256, 0, stream>>>(inp, embed, enorm,
                                               useT ? embedT : embed, useT,
                                               out, counts, diffacc);
    }
    k_fin<<<1, 256, 0, stream>>>(counts, diffacc, out);
}